// Round 1
// baseline (613.898 us; speedup 1.0000x reference)
//
#include <hip/hip_runtime.h>
#include <cstdint>
#include <cstddef>

#define NUM_C 81
#define NUM_A 16384

// Kernel 1: one wave (64 lanes) per anchor.
//  - compute ce = softplus(x) - t*x for the 81 classes, write to out (unmasked)
//  - wave-reduce max(ce) over the 81 classes
//  - apply "positive rows get 0" (depth != 0) and store max_ce[B*A] to workspace
__global__ __launch_bounds__(256)
void ce_max_kernel(const float* __restrict__ logits,
                   const float* __restrict__ target,
                   const int* __restrict__ depth,
                   float* __restrict__ out,
                   float* __restrict__ max_ce,
                   int n_anchors) {
    int wave = (int)((blockIdx.x * (unsigned)blockDim.x + threadIdx.x) >> 6);
    int lane = threadIdx.x & 63;
    if (wave >= n_anchors) return;
    size_t base = (size_t)wave * NUM_C;

    float x = logits[base + lane];
    float t = target[base + lane];
    // stable softplus: max(x,0) + log1p(exp(-|x|))
    float ce = fmaxf(x, 0.f) + log1pf(__builtin_expf(-fabsf(x))) - t * x;
    out[base + lane] = ce;
    float m = ce;

    if (lane < NUM_C - 64) {   // lanes 0..16 handle elements 64..80
        float x2 = logits[base + 64 + lane];
        float t2 = target[base + 64 + lane];
        float ce2 = fmaxf(x2, 0.f) + log1pf(__builtin_expf(-fabsf(x2))) - t2 * x2;
        out[base + 64 + lane] = ce2;
        m = fmaxf(m, ce2);
    }

    #pragma unroll
    for (int off = 32; off > 0; off >>= 1)
        m = fmaxf(m, __shfl_xor(m, off, 64));

    if (lane == 0) {
        // reference zeroes rows where depth != 0 before ranking
        max_ce[wave] = (depth[wave] != 0) ? 0.f : m;
    }
}

// Kernel 2: one block per batch row. Finds the top-K anchors by max_ce
// (K = min(negpos_ratio*num_pos, A-1)) with stable (index-order) tie-break,
// exactly matching the double-argsort rank trick, then zeroes out[b,a,:] for
// every anchor NOT in (positives | selected negatives).
__global__ __launch_bounds__(256)
void select_zero_kernel(const float* __restrict__ max_ce,
                        const int* __restrict__ depth,
                        const int* __restrict__ negpos_ratio,
                        float* __restrict__ out) {
    __shared__ unsigned int u[NUM_A];      // 64 KB: bit patterns (monotone, all >= 0)
    __shared__ int hist[256];
    __shared__ int red[4];
    __shared__ int thread_cnt[256];
    __shared__ unsigned int sh_prefix;
    __shared__ int sh_k;
    __shared__ int sh_g;
    __shared__ int sh_numpos;

    const int b   = blockIdx.x;
    const int tid = threadIdx.x;
    const float* mrow = max_ce + (size_t)b * NUM_A;
    const int*   drow = depth  + (size_t)b * NUM_A;

    // load row into LDS, count positives
    int pos = 0;
    for (int a = tid; a < NUM_A; a += 256) {
        u[a] = __float_as_uint(mrow[a]);   // all values >= 0 -> order-preserving
        pos += (drow[a] > 0);
    }
    #pragma unroll
    for (int off = 32; off > 0; off >>= 1) pos += __shfl_down(pos, off, 64);
    if ((tid & 63) == 0) red[tid >> 6] = pos;
    __syncthreads();
    if (tid == 0) sh_numpos = red[0] + red[1] + red[2] + red[3];
    __syncthreads();

    const int num_pos = sh_numpos;
    int K = negpos_ratio[0] * num_pos;
    if (K > NUM_A - 1) K = NUM_A - 1;

    unsigned int T;
    int eq_quota;
    if (K <= 0) {
        T = 0xFFFFFFFFu;      // unattainable for finite non-negative floats
        eq_quota = 0;
    } else {
        // 4-pass MSD radix select: find the K-th largest value (1-indexed)
        unsigned int prefix = 0;
        int k = K;
        for (int shift = 24; shift >= 0; shift -= 8) {
            hist[tid] = 0;
            __syncthreads();
            unsigned int himask = (shift == 24) ? 0u : (0xFFFFFFFFu << (shift + 8));
            for (int a = tid; a < NUM_A; a += 256) {
                unsigned int v = u[a];
                if ((v & himask) == (prefix & himask))
                    atomicAdd(&hist[(v >> shift) & 255], 1);
            }
            __syncthreads();
            if (tid == 0) {
                int acc = 0, bsel = 0, knew = k;
                for (int i = 255; i >= 0; --i) {
                    int h = hist[i];
                    if (acc + h >= k) { bsel = i; knew = k - acc; break; }
                    acc += h;
                }
                sh_prefix = prefix | ((unsigned)bsel << shift);
                sh_k = knew;
            }
            __syncthreads();
            prefix = sh_prefix;
            k = sh_k;
        }
        T = prefix;

        // g = #{v > T}; ties at T get the remaining quota in index order
        int gl = 0;
        for (int a = tid; a < NUM_A; a += 256) gl += (u[a] > T);
        #pragma unroll
        for (int off = 32; off > 0; off >>= 1) gl += __shfl_down(gl, off, 64);
        if ((tid & 63) == 0) red[tid >> 6] = gl;
        __syncthreads();
        if (tid == 0) sh_g = red[0] + red[1] + red[2] + red[3];
        __syncthreads();
        eq_quota = K - sh_g;
    }

    // stable prefix-count of ties: contiguous per-thread ranges (index order)
    const int per = NUM_A / 256;   // 64
    const int a0 = tid * per;
    int eqc = 0;
    for (int a = a0; a < a0 + per; ++a) eqc += (u[a] == T);
    thread_cnt[tid] = eqc;
    __syncthreads();
    if (tid == 0) {
        int acc = 0;
        for (int i = 0; i < 256; ++i) { int c = thread_cnt[i]; thread_cnt[i] = acc; acc += c; }
    }
    __syncthreads();
    int eqbase = thread_cnt[tid];

    float* orow = out + (size_t)b * NUM_A * NUM_C;
    for (int a = a0; a < a0 + per; ++a) {
        unsigned int v = u[a];
        bool selneg = (v > T);
        if (v == T) { selneg = (eqbase < eq_quota); eqbase++; }
        bool keep = (drow[a] > 0) || selneg;
        if (!keep) {
            float* p = orow + (size_t)a * NUM_C;
            #pragma unroll 9
            for (int c = 0; c < NUM_C; ++c) p[c] = 0.f;
        }
    }
}

extern "C" void kernel_launch(void* const* d_in, const int* in_sizes, int n_in,
                              void* d_out, int out_size, void* d_ws, size_t ws_size,
                              hipStream_t stream) {
    const float* logits = (const float*)d_in[0];
    const float* target = (const float*)d_in[1];
    const int*   depth  = (const int*)d_in[2];
    const int*   negpos = (const int*)d_in[3];
    float* out = (float*)d_out;
    float* max_ce = (float*)d_ws;           // needs B*A*4 = 2 MB of workspace

    const int n_anchors = in_sizes[2];      // B*A = 524288
    const int B = n_anchors / NUM_A;        // 32

    // 4 waves (=4 anchors) per 256-thread block
    int blocks = (n_anchors + 3) / 4;
    ce_max_kernel<<<blocks, 256, 0, stream>>>(logits, target, depth, out, max_ce, n_anchors);
    select_zero_kernel<<<B, 256, 0, stream>>>(max_ce, depth, negpos, out);
}

// Round 2
// 487.980 us; speedup vs baseline: 1.2580x; 1.2580x over previous
//
#include <hip/hip_runtime.h>
#include <cstdint>
#include <cstddef>

#define NUM_C 81
#define NUM_A 16384
#define A_TILE 128
#define TILE_ELEMS (A_TILE * NUM_C)      // 10368 floats
#define TILE_F4    (TILE_ELEMS / 4)      // 2592 float4

__device__ __forceinline__ float ce_one(float x, float t) {
    // softplus(x) - t*x, stable, HW transcendentals (v_exp_f32 / v_log_f32)
    float sp = fmaxf(x, 0.f) + __logf(1.f + __expf(-fabsf(x)));
    return fmaf(-t, x, sp);
}

// Kernel 1: 128 anchors per 256-thread block. float4-coalesced compute of
// ce -> out, staged in LDS; then per-anchor max (2 threads/anchor), with
// depth-zeroing, written to max_ce[B*A].
__global__ __launch_bounds__(256)
void ce_max_tile(const float* __restrict__ logits,
                 const float* __restrict__ target,
                 const int* __restrict__ depth,
                 float* __restrict__ out,
                 float* __restrict__ max_ce,
                 int n_anchors) {
    __shared__ float ce_s[TILE_ELEMS];   // 41472 B

    const int b = blockIdx.x;
    const size_t ebase = (size_t)b * TILE_ELEMS;
    const float4* lg4 = (const float4*)(logits + ebase);
    const float4* tg4 = (const float4*)(target + ebase);
    float4* o4 = (float4*)(out + ebase);
    float4* c4 = (float4*)ce_s;

    for (int i = threadIdx.x; i < TILE_F4; i += 256) {
        float4 x = lg4[i];
        float4 t = tg4[i];
        float4 c;
        c.x = ce_one(x.x, t.x);
        c.y = ce_one(x.y, t.y);
        c.z = ce_one(x.z, t.z);
        c.w = ce_one(x.w, t.w);
        o4[i] = c;
        c4[i] = c;
    }
    __syncthreads();

    // 2 threads per anchor: h=0 -> cols [0,41), h=1 -> cols [41,81)
    const int a = threadIdx.x >> 1;
    const int h = threadIdx.x & 1;
    const float* row = ce_s + a * NUM_C;
    const int c0 = h ? 41 : 0;
    const int c1 = h ? 81 : 41;
    float m = -1e30f;
    for (int c = c0; c < c1; ++c) m = fmaxf(m, row[c]);
    m = fmaxf(m, __shfl_xor(m, 1, 64));
    if (h == 0) {
        int ga = b * A_TILE + a;
        if (ga < n_anchors)
            max_ce[ga] = (depth[ga] != 0) ? 0.f : m;
    }
}

// Kernel 2: one block per batch row. Bisection top-K select (zero atomics),
// stable tie-break in index order, then zero non-kept anchor rows.
__global__ __launch_bounds__(256)
void select_zero_kernel(const float* __restrict__ max_ce,
                        const int* __restrict__ depth,
                        const int* __restrict__ negpos_ratio,
                        float* __restrict__ out) {
    __shared__ unsigned int u[NUM_A];    // 64 KB, swizzled uint4 layout
    __shared__ int red[4];
    __shared__ int wave_eq[4];

    const int b   = blockIdx.x;
    const int tid = threadIdx.x;
    const int lane = tid & 63;
    const int wid  = tid >> 6;
    const float* mrow = max_ce + (size_t)b * NUM_A;
    const int*   drow = depth  + (size_t)b * NUM_A;
    uint4* u4 = (uint4*)u;

    // Swizzle: logical uint4 index i stored at phys(i); keeps both strided
    // loads and per-thread contiguous chunk reads spread across banks.
    auto phys = [](int i) -> int {
        return (i & ~15) | (((i & 15) + (i >> 4)) & 15);
    };

    // ---- load row (coalesced) + count positives ----
    const uint4* m4 = (const uint4*)mrow;
    const int4*  d4 = (const int4*)drow;
    int pos = 0;
    for (int i = tid; i < NUM_A / 4; i += 256) {   // 16 iters
        uint4 v = m4[i];
        u4[phys(i)] = v;
        int4 dd = d4[i];
        pos += (dd.x > 0) + (dd.y > 0) + (dd.z > 0) + (dd.w > 0);
    }
    #pragma unroll
    for (int off = 32; off > 0; off >>= 1) pos += __shfl_down(pos, off, 64);
    if (lane == 0) red[wid] = pos;
    __syncthreads();
    const int num_pos = red[0] + red[1] + red[2] + red[3];

    int K = negpos_ratio[0] * num_pos;
    if (K > NUM_A - 1) K = NUM_A - 1;

    // ---- bisection: T = K-th largest bit pattern (all values >= 0) ----
    unsigned int T;
    int eq_quota;
    if (K <= 0) {
        T = 0xFFFFFFFFu;   // unattainable
        eq_quota = 0;
    } else {
        unsigned int p = 0;
        for (int bit = 31; bit >= 0; --bit) {
            unsigned int q = p | (1u << bit);
            int cnt = 0;
            #pragma unroll 4
            for (int j = 0; j < 16; ++j) {   // chunk-ordered (swizzled) reads
                uint4 v = u4[16 * tid + ((j + tid) & 15)];
                cnt += (v.x >= q) + (v.y >= q) + (v.z >= q) + (v.w >= q);
            }
            #pragma unroll
            for (int off = 32; off > 0; off >>= 1) cnt += __shfl_down(cnt, off, 64);
            __syncthreads();          // protect red[] from previous iter
            if (lane == 0) red[wid] = cnt;
            __syncthreads();
            int total = red[0] + red[1] + red[2] + red[3];
            if (total >= K) p = q;
        }
        T = p;

        // g = #{v > T}
        int gl = 0;
        #pragma unroll 4
        for (int j = 0; j < 16; ++j) {
            uint4 v = u4[16 * tid + ((j + tid) & 15)];
            gl += (v.x > T) + (v.y > T) + (v.z > T) + (v.w > T);
        }
        #pragma unroll
        for (int off = 32; off > 0; off >>= 1) gl += __shfl_down(gl, off, 64);
        __syncthreads();
        if (lane == 0) red[wid] = gl;
        __syncthreads();
        eq_quota = K - (red[0] + red[1] + red[2] + red[3]);
    }

    // ---- stable tie rank: exclusive prefix of (==T) counts, chunk order ----
    // thread t owns logical anchors [64t, 64t+64)
    int eqc = 0;
    #pragma unroll 4
    for (int j = 0; j < 16; ++j) {
        uint4 v = u4[16 * tid + ((j + tid) & 15)];
        eqc += (v.x == T) + (v.y == T) + (v.z == T) + (v.w == T);
    }
    int inc = eqc;
    #pragma unroll
    for (int off = 1; off < 64; off <<= 1) {
        int n = __shfl_up(inc, off, 64);
        if (lane >= off) inc += n;
    }
    if (lane == 63) wave_eq[wid] = inc;
    __syncthreads();
    int woff = 0;
    for (int w = 0; w < wid; ++w) woff += wave_eq[w];
    int eqr = woff + (inc - eqc);    // exclusive rank of my chunk's first tie

    // ---- zero rows not in (positives | selected negatives) ----
    float* orow = out + (size_t)b * NUM_A * NUM_C;
    const int base_a = tid * 64;
    for (int j = 0; j < 16; ++j) {   // logical order within chunk
        uint4 v = u4[16 * tid + ((j + tid) & 15)];
        unsigned int vv[4] = {v.x, v.y, v.z, v.w};
        #pragma unroll
        for (int e = 0; e < 4; ++e) {
            int aa = base_a + 4 * j + e;
            unsigned int x = vv[e];
            bool selneg = (x > T);
            if (x == T) { selneg = (eqr < eq_quota); eqr++; }
            bool keep = (drow[aa] > 0) || selneg;
            if (!keep) {
                float* p = orow + (size_t)aa * NUM_C;
                #pragma unroll 9
                for (int c = 0; c < NUM_C; ++c) p[c] = 0.f;
            }
        }
    }
}

extern "C" void kernel_launch(void* const* d_in, const int* in_sizes, int n_in,
                              void* d_out, int out_size, void* d_ws, size_t ws_size,
                              hipStream_t stream) {
    const float* logits = (const float*)d_in[0];
    const float* target = (const float*)d_in[1];
    const int*   depth  = (const int*)d_in[2];
    const int*   negpos = (const int*)d_in[3];
    float* out = (float*)d_out;
    float* max_ce = (float*)d_ws;            // B*A*4 = 2 MB scratch

    const int n_anchors = in_sizes[2];       // B*A = 524288
    const int B = n_anchors / NUM_A;         // 32

    int blocks1 = (n_anchors + A_TILE - 1) / A_TILE;   // 4096
    ce_max_tile<<<blocks1, 256, 0, stream>>>(logits, target, depth, out, max_ce, n_anchors);
    select_zero_kernel<<<B, 256, 0, stream>>>(max_ce, depth, negpos, out);
}